// Round 1
// baseline (213.514 us; speedup 1.0000x reference)
//
#include <hip/hip_runtime.h>
#include <math.h>

#define IN_DIM   128
#define OUT_DIM  128
#define N_NEIGH  32
#define BATCH    8192

// Kernel 1: fold the weight matrix into two 128-vectors + scalar.
// v1[i] = sum_o W_w[o,i]*u[o]; v2[i] = sum_o W_w[o,i]*u[128+o];
// c = sum_o W_b[o]*(u[o]+u[128+o]).
__global__ __launch_bounds__(128) void prep_kernel(const float* __restrict__ W_w,
                                                   const float* __restrict__ W_b,
                                                   const float* __restrict__ u,
                                                   float* __restrict__ ws) {
    int i = threadIdx.x;  // 0..127
    float a1 = 0.f, a2 = 0.f;
    for (int o = 0; o < OUT_DIM; ++o) {
        float w = W_w[o * IN_DIM + i];   // coalesced across i
        a1 += w * u[o];
        a2 += w * u[OUT_DIM + o];
    }
    ws[i] = a1;
    ws[IN_DIM + i] = a2;

    __shared__ float red[128];
    red[i] = W_b[i] * (u[i] + u[OUT_DIM + i]);
    __syncthreads();
    for (int s = 64; s > 0; s >>= 1) {
        if (i < s) red[i] += red[i + s];
        __syncthreads();
    }
    if (i == 0) ws[2 * IN_DIM] = red[0];
}

// Kernel 2: per batch element b, 33 dot products (32 neighbor rows + sq row),
// then softmax over the 32 neighbors.
__global__ __launch_bounds__(256) void gat_kernel(const float* __restrict__ ai_sq,
                                                  const float* __restrict__ ai_sn,
                                                  const float* __restrict__ ws,
                                                  float* __restrict__ out) {
    const int b    = blockIdx.x;
    const int tid  = threadIdx.x;
    const int half = tid >> 5;   // half-wave id 0..7
    const int c    = tid & 31;   // float4 chunk within a 128-float row

    __shared__ float t[33];      // t[0..31] = neighbor dots, t[32] = sq dot

    const float4* v1 = (const float4*)ws;
    const float4* v2 = (const float4*)(ws + IN_DIM);
    const float   cc = ws[2 * IN_DIM];

    const float4 v2c = v2[c];

    // rows 0..31: ai_sn[n, b, :] . v2 ; row 32: ai_sq[b, :] . v1
    for (int r = half; r < 33; r += 8) {
        float4 x, vv;
        if (r < 32) {
            x  = ((const float4*)(ai_sn + ((size_t)r * BATCH + b) * IN_DIM))[c];
            vv = v2c;
        } else {
            x  = ((const float4*)(ai_sq + (size_t)b * IN_DIM))[c];
            vv = v1[c];
        }
        float p = x.x * vv.x + x.y * vv.y + x.z * vv.z + x.w * vv.w;
        // reduce across the 32 lanes of this half-wave (xor of low 5 bits
        // stays inside the half)
        for (int m = 16; m > 0; m >>= 1) p += __shfl_xor(p, m);
        if (c == 0) t[r] = p;
    }
    __syncthreads();

    // softmax over n, done redundantly by both halves of wave 0
    if (tid < 64) {
        const int n = tid & 31;
        float mult = t[n] + t[32] + cc;
        float l = mult > 0.f ? mult : 0.01f * mult;
        float mx = l;
        for (int m = 16; m > 0; m >>= 1) mx = fmaxf(mx, __shfl_xor(mx, m));
        float e = expf(l - mx);
        float sum = e;
        for (int m = 16; m > 0; m >>= 1) sum += __shfl_xor(sum, m);
        if (tid < 32) out[(size_t)n * BATCH + b] = e / sum;
    }
}

extern "C" void kernel_launch(void* const* d_in, const int* in_sizes, int n_in,
                              void* d_out, int out_size, void* d_ws, size_t ws_size,
                              hipStream_t stream) {
    const float* ai_sq = (const float*)d_in[0];  // (8192, 128)
    const float* ai_sn = (const float*)d_in[1];  // (32, 8192, 128)
    const float* W_w   = (const float*)d_in[2];  // (128, 128)
    const float* W_b   = (const float*)d_in[3];  // (128,)
    const float* u     = (const float*)d_in[4];  // (256,)
    float* out = (float*)d_out;                  // (32, 8192)
    float* ws  = (float*)d_ws;                   // 257 floats used

    prep_kernel<<<1, 128, 0, stream>>>(W_w, W_b, u, ws);
    gat_kernel<<<BATCH, 256, 0, stream>>>(ai_sq, ai_sn, ws, out);
}

// Round 2
// 204.122 us; speedup vs baseline: 1.0460x; 1.0460x over previous
//
#include <hip/hip_runtime.h>
#include <math.h>

#define IN_DIM   128
#define OUT_DIM  128
#define N_NEIGH  32
#define BATCH    8192
#define B_TILE   8

// Fold the weight matrix into two 128-vectors + scalar:
// v1[i] = sum_o W_w[o,i]*u[o]; v2[i] = sum_o W_w[o,i]*u[128+o];
// c = sum_o W_b[o]*(u[o]+u[128+o]).
// 1024 threads: thread (i = t&127, g = t>>7) sums 16 o-values -> LDS reduce.
__global__ __launch_bounds__(1024) void prep_kernel(const float* __restrict__ W_w,
                                                    const float* __restrict__ W_b,
                                                    const float* __restrict__ u,
                                                    float* __restrict__ ws) {
    const int tid = threadIdx.x;
    const int i = tid & 127;
    const int g = tid >> 7;          // 0..7

    float a1 = 0.f, a2 = 0.f;
    #pragma unroll
    for (int oo = 0; oo < 16; ++oo) {
        int o = g * 16 + oo;
        float w = W_w[o * IN_DIM + i];   // coalesced across i
        a1 += w * u[o];
        a2 += w * u[OUT_DIM + o];
    }

    __shared__ float r1[8][128];
    __shared__ float r2[8][128];
    r1[g][i] = a1;
    r2[g][i] = a2;

    __shared__ float red[128];
    if (tid < 128) red[tid] = W_b[tid] * (u[tid] + u[OUT_DIM + tid]);
    __syncthreads();

    if (g == 0) {
        float s1 = 0.f, s2 = 0.f;
        #pragma unroll
        for (int gg = 0; gg < 8; ++gg) { s1 += r1[gg][i]; s2 += r2[gg][i]; }
        ws[i] = s1;
        ws[IN_DIM + i] = s2;
    }
    __syncthreads();
    if (tid == 0) {
        float s = 0.f;
        for (int k = 0; k < 128; ++k) s += red[k];
        ws[2 * IN_DIM] = s;
    }
}

// Each block handles B_TILE=8 batch elements. For each row r (32 neighbor
// rows + 1 sq row), a wave reads a contiguous 4KB chunk (8 rows x 512B) as
// 4 x 1KB vector loads; each 1KB load covers 2 rows (half-wave per row).
__global__ __launch_bounds__(256) void gat_kernel(const float* __restrict__ ai_sq,
                                                  const float* __restrict__ ai_sn,
                                                  const float* __restrict__ ws,
                                                  float* __restrict__ out) {
    const int b0   = blockIdx.x * B_TILE;
    const int tid  = threadIdx.x;
    const int wave = tid >> 6;       // 0..3
    const int lane = tid & 63;
    const int c    = lane & 31;      // float4 chunk within a 128-float row
    const int hb   = lane >> 5;      // which of the 2 rows in a 1KB load

    __shared__ float t[33][B_TILE + 1];   // +1 pad: kills softmax bank conflicts

    const float4* v1 = (const float4*)ws;
    const float4* v2 = (const float4*)(ws + IN_DIM);
    const float   cc = ws[2 * IN_DIM];
    const float4  v1c = v1[c];
    const float4  v2c = v2[c];

    for (int r = wave; r < 33; r += 4) {
        const float* base = (r < 32)
            ? (ai_sn + ((size_t)r * BATCH + b0) * IN_DIM)
            : (ai_sq + (size_t)b0 * IN_DIM);
        const float4 vv = (r < 32) ? v2c : v1c;
        #pragma unroll
        for (int k = 0; k < B_TILE / 2; ++k) {
            const int bl = k * 2 + hb;
            float4 x = ((const float4*)(base + (size_t)bl * IN_DIM))[c];
            float p = x.x * vv.x + x.y * vv.y + x.z * vv.z + x.w * vv.w;
            #pragma unroll
            for (int m = 16; m > 0; m >>= 1) p += __shfl_xor(p, m);
            if (c == 0) t[r][bl] = p;
        }
    }
    __syncthreads();

    // softmax over n: half-wave per batch element (n = tid&31, bl = tid>>5)
    const int n  = tid & 31;
    const int bl = tid >> 5;
    float mult = t[n][bl] + t[32][bl] + cc;
    float l = mult > 0.f ? mult : 0.01f * mult;
    float mx = l;
    #pragma unroll
    for (int m = 16; m > 0; m >>= 1) mx = fmaxf(mx, __shfl_xor(mx, m));
    float e = expf(l - mx);
    float s = e;
    #pragma unroll
    for (int m = 16; m > 0; m >>= 1) s += __shfl_xor(s, m);
    float res = e / s;
    __syncthreads();
    t[n][bl] = res;
    __syncthreads();

    // transpose out of LDS for contiguous 32B writes per 8 lanes
    const int nn = tid >> 3;
    const int bb = tid & 7;
    out[(size_t)nn * BATCH + b0 + bb] = t[nn][bb];
}

extern "C" void kernel_launch(void* const* d_in, const int* in_sizes, int n_in,
                              void* d_out, int out_size, void* d_ws, size_t ws_size,
                              hipStream_t stream) {
    const float* ai_sq = (const float*)d_in[0];  // (8192, 128)
    const float* ai_sn = (const float*)d_in[1];  // (32, 8192, 128)
    const float* W_w   = (const float*)d_in[2];  // (128, 128)
    const float* W_b   = (const float*)d_in[3];  // (128,)
    const float* u     = (const float*)d_in[4];  // (256,)
    float* out = (float*)d_out;                  // (32, 8192)
    float* ws  = (float*)d_ws;                   // 257 floats used

    prep_kernel<<<1, 1024, 0, stream>>>(W_w, W_b, u, ws);
    gat_kernel<<<BATCH / B_TILE, 256, 0, stream>>>(ai_sq, ai_sn, ws, out);
}